// Round 1
// baseline (22.501 us; speedup 1.0000x reference)
//
#include <hip/hip_runtime.h>
#include <math.h>

// Problem dims (fixed by reference setup_inputs):
// input[n=4][c=16][a=256], difference_mat[n][b=256][a][3], relative_mask[n][b][a],
// W[d=16][c=16][r=8], radii[r=8]  ->  out[n][d][b]  (float32)
constexpr int N = 4, B = 256, A = 256, C = 16, D = 16, RR = 8;
constexpr int DR = D * RR;           // 128
constexpr float GAMMA = 6.125f;

// Stage 1: P[n][d*8+r][a] = sum_c W[d][c][r] * input[n][c][a]
__global__ __launch_bounds__(256) void se3_compute_P(
    const float* __restrict__ input, const float* __restrict__ W,
    float* __restrict__ P)
{
    const int blk = blockIdx.x;          // n*DR + dr
    const int n  = blk / DR;
    const int dr = blk % DR;
    const int d  = dr / RR;
    const int r  = dr % RR;
    const int a  = threadIdx.x;

    float s = 0.f;
#pragma unroll
    for (int c = 0; c < C; ++c) {
        // W read is wave-uniform (scalar); input read is coalesced across lanes.
        s += W[(d * C + c) * RR + r] * input[(n * C + c) * A + a];
    }
    P[(size_t)blk * A + a] = s;
}

// Stage 2: out[n][d][b] = sum_{a,r} R[n,b,a,r] * P[n][d*8+r][a]
//   R = relative_mask[n,b,a] * exp(-GAMMA*(dist-radii[r])^2)
__global__ __launch_bounds__(256) void se3_compute_out(
    const float* __restrict__ P, const float* __restrict__ diff,
    const float* __restrict__ mask, const float* __restrict__ radii,
    float* __restrict__ out)
{
    const int blk = blockIdx.x;          // n*B + b
    const int n = blk / B;
    const int b = blk % B;
    const int a = threadIdx.x;

    const size_t nba = (size_t)(n * B + b) * A + a;
    const float* dp = diff + nba * 3;
    const float dx = dp[0], dy = dp[1], dz = dp[2];
    const float dist = sqrtf(dx * dx + dy * dy + dz * dz);
    const float m = mask[nba];

    float R[RR];
#pragma unroll
    for (int r = 0; r < RR; ++r) {
        const float t = dist - radii[r];
        R[r] = m * __expf(-GAMMA * t * t);
    }

    const float* Pn = P + (size_t)n * DR * A + a;
    float acc[D];
#pragma unroll
    for (int d = 0; d < D; ++d) acc[d] = 0.f;
#pragma unroll
    for (int d = 0; d < D; ++d) {
#pragma unroll
        for (int r = 0; r < RR; ++r) {
            acc[d] += R[r] * Pn[(d * RR + r) * A];   // coalesced across lanes
        }
    }

    // Block-reduce 16 d-partials over 256 threads (4 waves of 64).
    __shared__ float lds[4 * D];
    const int lane = threadIdx.x & 63;
    const int wave = threadIdx.x >> 6;
#pragma unroll
    for (int d = 0; d < D; ++d) {
        float v = acc[d];
#pragma unroll
        for (int off = 32; off > 0; off >>= 1)
            v += __shfl_down(v, off, 64);
        if (lane == 0) lds[wave * D + d] = v;
    }
    __syncthreads();
    if (threadIdx.x < D) {
        const int d = threadIdx.x;
        const float s = lds[d] + lds[D + d] + lds[2 * D + d] + lds[3 * D + d];
        out[(n * D + d) * B + b] = s;
    }
}

// Fallback (only if ws too small): fully fused, recomputes the c-contraction
// per (n,b,a) with W staged in LDS.
__global__ __launch_bounds__(256) void se3_fused(
    const float* __restrict__ input, const float* __restrict__ diff,
    const float* __restrict__ mask, const float* __restrict__ W,
    const float* __restrict__ radii, float* __restrict__ out)
{
    const int blk = blockIdx.x;          // n*B + b
    const int n = blk / B;
    const int b = blk % B;
    const int a = threadIdx.x;

    __shared__ float Wl[D * C * RR];     // 8 KB
    for (int i = threadIdx.x; i < D * C * RR; i += 256) Wl[i] = W[i];
    __syncthreads();

    const size_t nba = (size_t)(n * B + b) * A + a;
    const float* dp = diff + nba * 3;
    const float dx = dp[0], dy = dp[1], dz = dp[2];
    const float dist = sqrtf(dx * dx + dy * dy + dz * dz);
    const float m = mask[nba];

    float R[RR];
#pragma unroll
    for (int r = 0; r < RR; ++r) {
        const float t = dist - radii[r];
        R[r] = m * __expf(-GAMMA * t * t);
    }

    float acc[D];
#pragma unroll
    for (int d = 0; d < D; ++d) acc[d] = 0.f;
    for (int c = 0; c < C; ++c) {
        const float x = input[(n * C + c) * A + a];
        float xr[RR];
#pragma unroll
        for (int r = 0; r < RR; ++r) xr[r] = x * R[r];
#pragma unroll
        for (int d = 0; d < D; ++d) {
#pragma unroll
            for (int r = 0; r < RR; ++r)
                acc[d] += Wl[(d * C + c) * RR + r] * xr[r];
        }
    }

    __shared__ float lds[4 * D];
    const int lane = threadIdx.x & 63;
    const int wave = threadIdx.x >> 6;
#pragma unroll
    for (int d = 0; d < D; ++d) {
        float v = acc[d];
#pragma unroll
        for (int off = 32; off > 0; off >>= 1)
            v += __shfl_down(v, off, 64);
        if (lane == 0) lds[wave * D + d] = v;
    }
    __syncthreads();
    if (threadIdx.x < D) {
        const int d = threadIdx.x;
        const float s = lds[d] + lds[D + d] + lds[2 * D + d] + lds[3 * D + d];
        out[(n * D + d) * B + b] = s;
    }
}

extern "C" void kernel_launch(void* const* d_in, const int* in_sizes, int n_in,
                              void* d_out, int out_size, void* d_ws, size_t ws_size,
                              hipStream_t stream) {
    const float* input = (const float*)d_in[0];   // [N][C][A]
    const float* diff  = (const float*)d_in[1];   // [N][B][A][3]
    const float* mask  = (const float*)d_in[2];   // [N][B][A]
    const float* W     = (const float*)d_in[3];   // [D][C][RR]
    const float* radii = (const float*)d_in[4];   // [RR]
    float* out = (float*)d_out;                   // [N][D][B]

    const size_t needP = (size_t)N * DR * A * sizeof(float);  // 512 KB
    if (ws_size >= needP) {
        float* P = (float*)d_ws;
        se3_compute_P<<<N * DR, 256, 0, stream>>>(input, W, P);
        se3_compute_out<<<N * B, 256, 0, stream>>>(P, diff, mask, radii, out);
    } else {
        se3_fused<<<N * B, 256, 0, stream>>>(input, diff, mask, W, radii, out);
    }
}

// Round 2
// 16.118 us; speedup vs baseline: 1.3960x; 1.3960x over previous
//
#include <hip/hip_runtime.h>
#include <math.h>

// Problem dims (fixed by reference setup_inputs):
// input[n=4][c=16][a=256], difference_mat[n][b=256][a][3], relative_mask[n][b][a],
// W[d=16][c=16][r=8], radii[r=8]  ->  out[n][d][b]  (float32)
constexpr int N = 4, B = 256, A = 256, C = 16, D = 16, RR = 8;
constexpr int DR = D * RR;           // 128
constexpr int BT = 4;                // b-tile per block in stage 2
constexpr float GAMMA = 6.125f;

// Stage 1: P[n][d*8+r][a] = sum_c W[d][c][r] * input[n][c][a]
__global__ __launch_bounds__(256) void se3_compute_P(
    const float* __restrict__ input, const float* __restrict__ W,
    float* __restrict__ P)
{
    const int blk = blockIdx.x;          // n*DR + dr
    const int n  = blk / DR;
    const int dr = blk % DR;
    const int d  = dr / RR;
    const int r  = dr % RR;
    const int a  = threadIdx.x;

    float s = 0.f;
#pragma unroll
    for (int c = 0; c < C; ++c) {
        // W read is wave-uniform (scalar); input read is coalesced across lanes.
        s += W[(d * C + c) * RR + r] * input[(n * C + c) * A + a];
    }
    P[(size_t)blk * A + a] = s;
}

// Stage 2 v3: out[n][d][b] = sum_{a,r} R[n,b,a,r] * P[n][d*8+r][a]
// Block = (n, 4 consecutive b). Thread owns one a; P column held in 128 VGPRs,
// reused for all 4 b. Reduction over lanes via fold (halving xor steps) that
// simultaneously distributes the 16 d-sums across lane groups.
__global__ __launch_bounds__(256) void se3_compute_out(
    const float* __restrict__ P, const float* __restrict__ diff,
    const float* __restrict__ mask, const float* __restrict__ radii,
    float* __restrict__ out)
{
    const int blk = blockIdx.x;          // n*(B/BT) + bg
    const int n  = blk / (B / BT);
    const int b0 = (blk % (B / BT)) * BT;
    const int a  = threadIdx.x;
    const int lane = threadIdx.x & 63;
    const int wave = threadIdx.x >> 6;

    float rad[RR];
#pragma unroll
    for (int r = 0; r < RR; ++r) rad[r] = radii[r];   // wave-uniform -> s_loads

    // P column for this a: 128 coalesced dword loads, lives in VGPRs.
    float preg[DR];
    const float* Pn = P + (size_t)n * DR * A + a;
#pragma unroll
    for (int dr = 0; dr < DR; ++dr) preg[dr] = Pn[dr * A];

    __shared__ float lds[BT][4][D];      // per-b slab -> one sync total

#pragma unroll
    for (int bi = 0; bi < BT; ++bi) {
        const int b = b0 + bi;
        const size_t nba = (size_t)(n * B + b) * A + a;
        const float* dp = diff + nba * 3;
        const float dx = dp[0], dy = dp[1], dz = dp[2];
        const float dist = sqrtf(dx * dx + dy * dy + dz * dz);
        const float m = mask[nba];

        float R[RR];
#pragma unroll
        for (int r = 0; r < RR; ++r) {
            const float t = dist - rad[r];
            R[r] = m * __expf(-GAMMA * t * t);
        }

        float acc[D];
#pragma unroll
        for (int d = 0; d < D; ++d) {
            float s = 0.f;
#pragma unroll
            for (int r = 0; r < RR; ++r) s += R[r] * preg[d * RR + r];
            acc[d] = s;
        }

        // Fold-reduce across 64 lanes. After the 4 halving steps, lane l holds
        // in acc[0] the partial (over the 16 lanes with equal l&3) for
        // d = (l>>2)&15; two more xor steps complete the 64-lane sum.
        {
            const bool hi32 = (lane & 32) != 0;
#pragma unroll
            for (int i = 0; i < 8; ++i) {
                float send = hi32 ? acc[i] : acc[i + 8];
                float recv = __shfl_xor(send, 32, 64);
                acc[i] = (hi32 ? acc[i + 8] : acc[i]) + recv;
            }
        }
        {
            const bool hi16 = (lane & 16) != 0;
#pragma unroll
            for (int i = 0; i < 4; ++i) {
                float send = hi16 ? acc[i] : acc[i + 4];
                float recv = __shfl_xor(send, 16, 64);
                acc[i] = (hi16 ? acc[i + 4] : acc[i]) + recv;
            }
        }
        {
            const bool hi8 = (lane & 8) != 0;
#pragma unroll
            for (int i = 0; i < 2; ++i) {
                float send = hi8 ? acc[i] : acc[i + 2];
                float recv = __shfl_xor(send, 8, 64);
                acc[i] = (hi8 ? acc[i + 2] : acc[i]) + recv;
            }
        }
        {
            const bool hi4 = (lane & 4) != 0;
            float send = hi4 ? acc[0] : acc[1];
            float recv = __shfl_xor(send, 4, 64);
            acc[0] = (hi4 ? acc[1] : acc[0]) + recv;
        }
        float v = acc[0];
        v += __shfl_xor(v, 1, 64);
        v += __shfl_xor(v, 2, 64);
        if ((lane & 3) == 0) lds[bi][wave][(lane >> 2) & 15] = v;
    }
    __syncthreads();

    if (threadIdx.x < BT * D) {
        const int bi = threadIdx.x / D;
        const int d  = threadIdx.x % D;
        const float s = lds[bi][0][d] + lds[bi][1][d] + lds[bi][2][d] + lds[bi][3][d];
        out[(n * D + d) * B + (b0 + bi)] = s;
    }
}

// Fallback (only if ws too small): fully fused, recomputes the c-contraction
// per (n,b,a) with W staged in LDS.
__global__ __launch_bounds__(256) void se3_fused(
    const float* __restrict__ input, const float* __restrict__ diff,
    const float* __restrict__ mask, const float* __restrict__ W,
    const float* __restrict__ radii, float* __restrict__ out)
{
    const int blk = blockIdx.x;          // n*B + b
    const int n = blk / B;
    const int b = blk % B;
    const int a = threadIdx.x;

    __shared__ float Wl[D * C * RR];     // 8 KB
    for (int i = threadIdx.x; i < D * C * RR; i += 256) Wl[i] = W[i];
    __syncthreads();

    const size_t nba = (size_t)(n * B + b) * A + a;
    const float* dp = diff + nba * 3;
    const float dx = dp[0], dy = dp[1], dz = dp[2];
    const float dist = sqrtf(dx * dx + dy * dy + dz * dz);
    const float m = mask[nba];

    float R[RR];
#pragma unroll
    for (int r = 0; r < RR; ++r) {
        const float t = dist - radii[r];
        R[r] = m * __expf(-GAMMA * t * t);
    }

    float acc[D];
#pragma unroll
    for (int d = 0; d < D; ++d) acc[d] = 0.f;
    for (int c = 0; c < C; ++c) {
        const float x = input[(n * C + c) * A + a];
        float xr[RR];
#pragma unroll
        for (int r = 0; r < RR; ++r) xr[r] = x * R[r];
#pragma unroll
        for (int d = 0; d < D; ++d) {
#pragma unroll
            for (int r = 0; r < RR; ++r)
                acc[d] += Wl[(d * C + c) * RR + r] * xr[r];
        }
    }

    __shared__ float lds[4 * D];
    const int lane = threadIdx.x & 63;
    const int wave = threadIdx.x >> 6;
#pragma unroll
    for (int d = 0; d < D; ++d) {
        float v = acc[d];
#pragma unroll
        for (int off = 32; off > 0; off >>= 1)
            v += __shfl_down(v, off, 64);
        if (lane == 0) lds[wave * D + d] = v;
    }
    __syncthreads();
    if (threadIdx.x < D) {
        const int d = threadIdx.x;
        const float s = lds[d] + lds[D + d] + lds[2 * D + d] + lds[3 * D + d];
        out[(n * D + d) * B + b] = s;
    }
}

extern "C" void kernel_launch(void* const* d_in, const int* in_sizes, int n_in,
                              void* d_out, int out_size, void* d_ws, size_t ws_size,
                              hipStream_t stream) {
    const float* input = (const float*)d_in[0];   // [N][C][A]
    const float* diff  = (const float*)d_in[1];   // [N][B][A][3]
    const float* mask  = (const float*)d_in[2];   // [N][B][A]
    const float* W     = (const float*)d_in[3];   // [D][C][RR]
    const float* radii = (const float*)d_in[4];   // [RR]
    float* out = (float*)d_out;                   // [N][D][B]

    const size_t needP = (size_t)N * DR * A * sizeof(float);  // 512 KB
    if (ws_size >= needP) {
        float* P = (float*)d_ws;
        se3_compute_P<<<N * DR, 256, 0, stream>>>(input, W, P);
        se3_compute_out<<<N * (B / BT), 256, 0, stream>>>(P, diff, mask, radii, out);
    } else {
        se3_fused<<<N * B, 256, 0, stream>>>(input, diff, mask, W, radii, out);
    }
}